// Round 1
// baseline (557.191 us; speedup 1.0000x reference)
//
#include <hip/hip_runtime.h>

constexpr int kB = 4, kC = 64, kH = 64, kW = 64, kN = kH * kW;
constexpr float kEps = 1e-5f;

// ---- w[oc][ic][kh][kw] -> wt[(ic*9+kh*3+kw)*64 + oc] (coalesced staging later)
__global__ __launch_bounds__(256) void transpose_w_kernel(const float* __restrict__ w,
                                                          float* __restrict__ wt) {
  int idx = blockIdx.x * 256 + threadIdx.x;
  if (idx < kC * kC * 9) {
    int oc = idx & 63;
    int r = idx >> 6;
    wt[idx] = w[oc * (kC * 9) + r];
  }
}

// ---- conv 3x3 SAME + bias: y[b][oc][h][w]; block = (b,h), thread: oc=tid>>2, 16 w's
__global__ __launch_bounds__(256) void conv_kernel(const float* __restrict__ x,
                                                   const float* __restrict__ wt,
                                                   const float* __restrict__ bias,
                                                   float* __restrict__ y) {
  const int tid = threadIdx.x;
  const int b = blockIdx.x >> 6;
  const int h = blockIdx.x & 63;
  const int oc = tid >> 2;
  const int wbase = (tid & 3) * 16;

  __shared__ float xs[3][16][68];      // [kh][ic][1+w], padded rows (16B-aligned rows)
  __shared__ float wl[16 * 9 * 64];    // [ic][kh][kw][oc]

  float acc[16];
#pragma unroll
  for (int k = 0; k < 16; ++k) acc[k] = 0.f;

  for (int chunk = 0; chunk < 4; ++chunk) {
    const int ic0 = chunk * 16;
    for (int idx = tid; idx < 3 * 16 * 64; idx += 256) {
      int kh = idx / (16 * 64);
      int rem = idx - kh * (16 * 64);
      int ic = rem >> 6;
      int wv = rem & 63;
      int hh = h + kh - 1;
      float v = 0.f;
      if (hh >= 0 && hh < kH) v = x[((b * kC + ic0 + ic) * kH + hh) * kW + wv];
      xs[kh][ic][1 + wv] = v;
    }
    if (tid < 48) {
      int kh = tid / 16, ic = tid & 15;
      xs[kh][ic][0] = 0.f;
      xs[kh][ic][65] = 0.f;
      xs[kh][ic][66] = 0.f;
      xs[kh][ic][67] = 0.f;
    }
    {
      const float4* src = (const float4*)(wt + ic0 * (9 * 64));
      float4* dst = (float4*)wl;
      for (int idx = tid; idx < 16 * 9 * 64 / 4; idx += 256) dst[idx] = src[idx];
    }
    __syncthreads();

    for (int ic = 0; ic < 16; ++ic) {
#pragma unroll
      for (int kh = 0; kh < 3; ++kh) {
        float xr[20];
        const float* xrow = &xs[kh][ic][0];
#pragma unroll
        for (int m = 0; m < 5; ++m)
          *(float4*)&xr[m * 4] = *(const float4*)&xrow[wbase + m * 4];
        const float* wrow = &wl[(ic * 9 + kh * 3) * 64 + oc];
#pragma unroll
        for (int kw = 0; kw < 3; ++kw) {
          float wv = wrow[kw * 64];
#pragma unroll
          for (int k = 0; k < 16; ++k) acc[k] = fmaf(wv, xr[k + kw], acc[k]);
        }
      }
    }
    __syncthreads();
  }
  const float bv = bias[oc];
  float* yp = y + ((b * kC + oc) * kH + h) * kW + wbase;
#pragma unroll
  for (int m = 0; m < 4; ++m) {
    float4 v = {acc[m * 4 + 0] + bv, acc[m * 4 + 1] + bv,
                acc[m * 4 + 2] + bv, acc[m * 4 + 3] + bv};
    *(float4*)(yp + m * 4) = v;
  }
}

// ---- per-channel batch stats -> A[c]=scale*rsqrt(var+eps), B[c]=bias-mean*A
__global__ __launch_bounds__(256) void stats_kernel(const float* __restrict__ y,
                                                    const float* __restrict__ scale,
                                                    const float* __restrict__ bias,
                                                    float* __restrict__ AB) {
  const int c = blockIdx.x;
  const int tid = threadIdx.x;
  float s = 0.f, s2 = 0.f;
  for (int b = 0; b < kB; ++b) {
    const float* p = y + (b * kC + c) * kN;
    for (int i = tid * 4; i < kN; i += 1024) {
      float4 v = *(const float4*)(p + i);
      s += v.x + v.y + v.z + v.w;
      s2 += v.x * v.x + v.y * v.y + v.z * v.z + v.w * v.w;
    }
  }
  __shared__ float rs[256], rq[256];
  rs[tid] = s;
  rq[tid] = s2;
  __syncthreads();
  for (int off = 128; off > 0; off >>= 1) {
    if (tid < off) { rs[tid] += rs[tid + off]; rq[tid] += rq[tid + off]; }
    __syncthreads();
  }
  if (tid == 0) {
    const float inv_n = 1.f / (float)(kB * kN);
    float mean = rs[0] * inv_n;
    float var = rq[0] * inv_n - mean * mean;
    float A = scale[c] * rsqrtf(var + kEps);
    AB[c] = A;
    AB[kC + c] = bias[c] - mean * A;
  }
}

// ---- BN affine + PReLU -> feat
__global__ __launch_bounds__(256) void bn_prelu_kernel(const float* __restrict__ y,
                                                       const float* __restrict__ AB,
                                                       const float* __restrict__ pa,
                                                       float* __restrict__ feat) {
  int idx = (blockIdx.x * 256 + threadIdx.x) * 4;
  int c = (idx >> 12) & 63;
  float A = AB[c], Bc = AB[kC + c];
  float a = pa[0];
  float4 v = *(const float4*)(y + idx);
  float4 r;
  r.x = fmaf(A, v.x, Bc); r.x = r.x >= 0.f ? r.x : a * r.x;
  r.y = fmaf(A, v.y, Bc); r.y = r.y >= 0.f ? r.y : a * r.y;
  r.z = fmaf(A, v.z, Bc); r.z = r.z >= 0.f ? r.z : a * r.z;
  r.w = fmaf(A, v.w, Bc); r.w = r.w >= 0.f ? r.w : a * r.w;
  *(float4*)(feat + idx) = r;
}

// ---- flash-style attention: block = (b, i-tile of 64); out = gamma*(PV/l) + feat
__global__ __launch_bounds__(256) void attn_kernel(const float* __restrict__ feat,
                                                   const float* __restrict__ gamma_p,
                                                   float* __restrict__ out) {
  const int tid = threadIdx.x;
  const int b = blockIdx.x >> 6;
  const int i0 = (blockIdx.x & 63) << 6;
  const float* f = feat + b * (kC * kN);

  __shared__ float Qs[64][64];
  __shared__ float Ks[64][64];   // also the V tile
  __shared__ float Ps[64][68];
  __shared__ float pmaxT[64][17];
  __shared__ float psumT[64][17];
  __shared__ float mrow[64], lrow[64], arow[64];

  const int ti = tid >> 4, tj = tid & 15;

  for (int idx = tid * 4; idx < 4096; idx += 1024) {
    int c = idx >> 6, i = idx & 63;
    *(float4*)&Qs[c][i] = *(const float4*)(f + c * kN + i0 + i);
  }
  if (tid < 64) { mrow[tid] = -1e30f; lrow[tid] = 0.f; }

  float o[4][4];
#pragma unroll
  for (int a = 0; a < 4; ++a)
#pragma unroll
    for (int bb = 0; bb < 4; ++bb) o[a][bb] = 0.f;

  for (int jt = 0; jt < 64; ++jt) {
    const int j0 = jt << 6;
    __syncthreads();  // Ks / Ps free from previous iteration
    for (int idx = tid * 4; idx < 4096; idx += 1024) {
      int c = idx >> 6, j = idx & 63;
      *(float4*)&Ks[c][j] = *(const float4*)(f + c * kN + j0 + j);
    }
    __syncthreads();

    // S tile: s[a][bb] = energy(i=ti*4+a, j=tj*4+bb)
    float s[4][4];
#pragma unroll
    for (int a = 0; a < 4; ++a)
#pragma unroll
      for (int bb = 0; bb < 4; ++bb) s[a][bb] = 0.f;
#pragma unroll 4
    for (int c = 0; c < 64; ++c) {
      float4 q = *(float4*)&Qs[c][ti << 2];
      float4 k = *(float4*)&Ks[c][tj << 2];
      float qa[4] = {q.x, q.y, q.z, q.w};
      float ka[4] = {k.x, k.y, k.z, k.w};
#pragma unroll
      for (int a = 0; a < 4; ++a)
#pragma unroll
        for (int bb = 0; bb < 4; ++bb) s[a][bb] = fmaf(qa[a], ka[bb], s[a][bb]);
    }
    // z = -s; per-thread partial row maxes
#pragma unroll
    for (int a = 0; a < 4; ++a) {
      float m0 = fmaxf(fmaxf(-s[a][0], -s[a][1]), fmaxf(-s[a][2], -s[a][3]));
      pmaxT[(ti << 2) + a][tj] = m0;
    }
    __syncthreads();
    if (tid < 64) {
      float m = mrow[tid];
      float mt = pmaxT[tid][0];
#pragma unroll
      for (int q = 1; q < 16; ++q) mt = fmaxf(mt, pmaxT[tid][q]);
      float mn = fmaxf(m, mt);
      arow[tid] = __expf(m - mn);
      mrow[tid] = mn;
    }
    __syncthreads();
    // exp, write P, partial sums; rescale O by alpha
#pragma unroll
    for (int a = 0; a < 4; ++a) {
      float mn = mrow[(ti << 2) + a];
      float4 pv;
      pv.x = __expf(-s[a][0] - mn);
      pv.y = __expf(-s[a][1] - mn);
      pv.z = __expf(-s[a][2] - mn);
      pv.w = __expf(-s[a][3] - mn);
      *(float4*)&Ps[(ti << 2) + a][tj << 2] = pv;
      psumT[(ti << 2) + a][tj] = pv.x + pv.y + pv.z + pv.w;
    }
#pragma unroll
    for (int ii = 0; ii < 4; ++ii) {
      float al = arow[(tj << 2) + ii];
#pragma unroll
      for (int cc = 0; cc < 4; ++cc) o[cc][ii] *= al;
    }
    __syncthreads();
    if (tid < 64) {
      float acc = 0.f;
#pragma unroll
      for (int q = 0; q < 16; ++q) acc += psumT[tid][q];
      lrow[tid] = lrow[tid] * arow[tid] + acc;
    }
    // PV: o[cc][ii] += sum_j P[tj*4+ii][j] * V[ti*4+cc][j]
#pragma unroll 2
    for (int jq = 0; jq < 16; ++jq) {
      float4 pr[4];
#pragma unroll
      for (int ii = 0; ii < 4; ++ii) pr[ii] = *(float4*)&Ps[(tj << 2) + ii][jq << 2];
#pragma unroll
      for (int cc = 0; cc < 4; ++cc) {
        float4 vv = *(float4*)&Ks[(ti << 2) + cc][jq << 2];
#pragma unroll
        for (int ii = 0; ii < 4; ++ii)
          o[cc][ii] += pr[ii].x * vv.x + pr[ii].y * vv.y + pr[ii].z * vv.z +
                       pr[ii].w * vv.w;
      }
    }
  }
  __syncthreads();
  const float g = gamma_p[0];
  float rl[4];
#pragma unroll
  for (int ii = 0; ii < 4; ++ii) rl[ii] = 1.f / lrow[(tj << 2) + ii];
#pragma unroll
  for (int cc = 0; cc < 4; ++cc) {
    int c = (ti << 2) + cc;
    float4 ov;
    ov.x = g * (o[cc][0] * rl[0]) + Qs[c][(tj << 2) + 0];
    ov.y = g * (o[cc][1] * rl[1]) + Qs[c][(tj << 2) + 1];
    ov.z = g * (o[cc][2] * rl[2]) + Qs[c][(tj << 2) + 2];
    ov.w = g * (o[cc][3] * rl[3]) + Qs[c][(tj << 2) + 3];
    *(float4*)(out + (b * kC + c) * kN + i0 + (tj << 2)) = ov;
  }
}

extern "C" void kernel_launch(void* const* d_in, const int* in_sizes, int n_in,
                              void* d_out, int out_size, void* d_ws, size_t ws_size,
                              hipStream_t stream) {
  (void)in_sizes; (void)n_in; (void)out_size; (void)ws_size;
  const float* x        = (const float*)d_in[0];
  const float* conv_w   = (const float*)d_in[1];
  const float* conv_b   = (const float*)d_in[2];
  const float* bn_scale = (const float*)d_in[3];
  const float* bn_bias  = (const float*)d_in[4];
  const float* prelu_a  = (const float*)d_in[5];
  const float* gamma    = (const float*)d_in[6];
  float* out = (float*)d_out;

  float* feat = (float*)d_ws;                         // 1M floats (4 MB)
  float* AB   = feat + kB * kC * kN;                  // 128 floats
  float* wt   = AB + 256;                             // 36864 floats

  float* y = out;  // use d_out as conv scratch; fully overwritten by attn at the end

  transpose_w_kernel<<<144, 256, 0, stream>>>(conv_w, wt);
  conv_kernel<<<kB * kH, 256, 0, stream>>>(x, wt, conv_b, y);
  stats_kernel<<<kC, 256, 0, stream>>>(y, bn_scale, bn_bias, AB);
  bn_prelu_kernel<<<(kB * kC * kN) / 1024, 256, 0, stream>>>(y, AB, prelu_a, feat);
  attn_kernel<<<kB * (kN / 64), 256, 0, stream>>>(feat, gamma, out);
}

// Round 2
// 198.547 us; speedup vs baseline: 2.8063x; 2.8063x over previous
//
#include <hip/hip_runtime.h>

constexpr int kB = 4, kC = 64, kH = 64, kW = 64, kN = kH * kW;
constexpr float kEps = 1e-5f;

typedef __attribute__((ext_vector_type(8))) short short8;
typedef __attribute__((ext_vector_type(4))) float f32x4;

__device__ inline unsigned pkbf(float a, float b) {
  unsigned ua = __float_as_uint(a), ub = __float_as_uint(b);
  ua += 0x7fff + ((ua >> 16) & 1);
  ub += 0x7fff + ((ub >> 16) & 1);
  return (ua >> 16) | (ub & 0xffff0000u);
}

// ---- w[oc][ic][kh][kw] -> wt[(ic*9+kh*3+kw)*64 + oc]
__global__ __launch_bounds__(256) void transpose_w_kernel(const float* __restrict__ w,
                                                          float* __restrict__ wt) {
  int idx = blockIdx.x * 256 + threadIdx.x;
  if (idx < kC * kC * 9) {
    int oc = idx & 63;
    int r = idx >> 6;
    wt[idx] = w[oc * (kC * 9) + r];
  }
}

// ---- conv 3x3 SAME + bias (unchanged from R1, passed)
__global__ __launch_bounds__(256) void conv_kernel(const float* __restrict__ x,
                                                   const float* __restrict__ wt,
                                                   const float* __restrict__ bias,
                                                   float* __restrict__ y) {
  const int tid = threadIdx.x;
  const int b = blockIdx.x >> 6;
  const int h = blockIdx.x & 63;
  const int oc = tid >> 2;
  const int wbase = (tid & 3) * 16;

  __shared__ float xs[3][16][68];
  __shared__ float wl[16 * 9 * 64];

  float acc[16];
#pragma unroll
  for (int k = 0; k < 16; ++k) acc[k] = 0.f;

  for (int chunk = 0; chunk < 4; ++chunk) {
    const int ic0 = chunk * 16;
    for (int idx = tid; idx < 3 * 16 * 64; idx += 256) {
      int kh = idx / (16 * 64);
      int rem = idx - kh * (16 * 64);
      int ic = rem >> 6;
      int wv = rem & 63;
      int hh = h + kh - 1;
      float v = 0.f;
      if (hh >= 0 && hh < kH) v = x[((b * kC + ic0 + ic) * kH + hh) * kW + wv];
      xs[kh][ic][1 + wv] = v;
    }
    if (tid < 48) {
      int kh = tid / 16, ic = tid & 15;
      xs[kh][ic][0] = 0.f;
      xs[kh][ic][65] = 0.f;
      xs[kh][ic][66] = 0.f;
      xs[kh][ic][67] = 0.f;
    }
    {
      const float4* src = (const float4*)(wt + ic0 * (9 * 64));
      float4* dst = (float4*)wl;
      for (int idx = tid; idx < 16 * 9 * 64 / 4; idx += 256) dst[idx] = src[idx];
    }
    __syncthreads();

    for (int ic = 0; ic < 16; ++ic) {
#pragma unroll
      for (int kh = 0; kh < 3; ++kh) {
        float xr[20];
        const float* xrow = &xs[kh][ic][0];
#pragma unroll
        for (int m = 0; m < 5; ++m)
          *(float4*)&xr[m * 4] = *(const float4*)&xrow[wbase + m * 4];
        const float* wrow = &wl[(ic * 9 + kh * 3) * 64 + oc];
#pragma unroll
        for (int kw = 0; kw < 3; ++kw) {
          float wv = wrow[kw * 64];
#pragma unroll
          for (int k = 0; k < 16; ++k) acc[k] = fmaf(wv, xr[k + kw], acc[k]);
        }
      }
    }
    __syncthreads();
  }
  const float bv = bias[oc];
  float* yp = y + ((b * kC + oc) * kH + h) * kW + wbase;
#pragma unroll
  for (int m = 0; m < 4; ++m) {
    float4 v = {acc[m * 4 + 0] + bv, acc[m * 4 + 1] + bv,
                acc[m * 4 + 2] + bv, acc[m * 4 + 3] + bv};
    *(float4*)(yp + m * 4) = v;
  }
}

// ---- per-channel batch stats -> A[c], B[c]
__global__ __launch_bounds__(256) void stats_kernel(const float* __restrict__ y,
                                                    const float* __restrict__ scale,
                                                    const float* __restrict__ bias,
                                                    float* __restrict__ AB) {
  const int c = blockIdx.x;
  const int tid = threadIdx.x;
  float s = 0.f, s2 = 0.f;
  for (int b = 0; b < kB; ++b) {
    const float* p = y + (b * kC + c) * kN;
    for (int i = tid * 4; i < kN; i += 1024) {
      float4 v = *(const float4*)(p + i);
      s += v.x + v.y + v.z + v.w;
      s2 += v.x * v.x + v.y * v.y + v.z * v.z + v.w * v.w;
    }
  }
  __shared__ float rs[256], rq[256];
  rs[tid] = s;
  rq[tid] = s2;
  __syncthreads();
  for (int off = 128; off > 0; off >>= 1) {
    if (tid < off) { rs[tid] += rs[tid + off]; rq[tid] += rq[tid + off]; }
    __syncthreads();
  }
  if (tid == 0) {
    const float inv_n = 1.f / (float)(kB * kN);
    float mean = rs[0] * inv_n;
    float var = rq[0] * inv_n - mean * mean;
    float A = scale[c] * rsqrtf(var + kEps);
    AB[c] = A;
    AB[kC + c] = bias[c] - mean * A;
  }
}

// ---- BN + PReLU -> feat (f32 [c][n]), fbf (bf16 [c][n]), fbfT (bf16 [n][c])
__global__ __launch_bounds__(256) void pack_kernel(const float* __restrict__ y,
                                                   const float* __restrict__ AB,
                                                   const float* __restrict__ pa,
                                                   float* __restrict__ feat,
                                                   unsigned short* __restrict__ fbf,
                                                   unsigned short* __restrict__ fbfT) {
  __shared__ float ls[64 * 65];
  const int tid = threadIdx.x;
  const int b = blockIdx.x >> 6;
  const int n0 = (blockIdx.x & 63) << 6;
  {
    const int c = tid >> 2, nj = (tid & 3) << 4;
    const float A = AB[c], Bc = AB[kC + c], a = pa[0];
    const float* yp = y + ((b * kC + c) * kN) + n0 + nj;
    float f[16];
#pragma unroll
    for (int v = 0; v < 4; ++v) {
      float4 xv = *(const float4*)(yp + v * 4);
      float t;
      t = fmaf(A, xv.x, Bc); f[v * 4 + 0] = t >= 0.f ? t : a * t;
      t = fmaf(A, xv.y, Bc); f[v * 4 + 1] = t >= 0.f ? t : a * t;
      t = fmaf(A, xv.z, Bc); f[v * 4 + 2] = t >= 0.f ? t : a * t;
      t = fmaf(A, xv.w, Bc); f[v * 4 + 3] = t >= 0.f ? t : a * t;
    }
    float* fo = feat + ((b * kC + c) * kN) + n0 + nj;
#pragma unroll
    for (int v = 0; v < 4; ++v) {
      float4 fv = {f[v * 4 + 0], f[v * 4 + 1], f[v * 4 + 2], f[v * 4 + 3]};
      *(float4*)(fo + v * 4) = fv;
    }
    unsigned short* fb = fbf + ((b * kC + c) * kN) + n0 + nj;
    uint4 p0 = {pkbf(f[0], f[1]), pkbf(f[2], f[3]), pkbf(f[4], f[5]), pkbf(f[6], f[7])};
    uint4 p1 = {pkbf(f[8], f[9]), pkbf(f[10], f[11]), pkbf(f[12], f[13]), pkbf(f[14], f[15])};
    *(uint4*)(fb) = p0;
    *(uint4*)(fb + 8) = p1;
#pragma unroll
    for (int v = 0; v < 16; ++v) ls[c * 65 + nj + v] = f[v];
  }
  __syncthreads();
  {
    const int n = tid >> 2, cc = (tid & 3) << 4;
    float g[16];
#pragma unroll
    for (int v = 0; v < 16; ++v) g[v] = ls[(cc + v) * 65 + n];
    unsigned short* ft = fbfT + b * (kN * kC) + (n0 + n) * 64 + cc;
    uint4 o0 = {pkbf(g[0], g[1]), pkbf(g[2], g[3]), pkbf(g[4], g[5]), pkbf(g[6], g[7])};
    uint4 o1 = {pkbf(g[8], g[9]), pkbf(g[10], g[11]), pkbf(g[12], g[13]), pkbf(g[14], g[15])};
    *(uint4*)(ft) = o0;
    *(uint4*)(ft + 8) = o1;
  }
}

// ---- MFMA flash attention, no-max softmax (shift-invariant), 16x16x32 bf16
// block = (b, i-tile 64); wave w owns i rows [i0+16w, i0+16w+16)
__global__ __launch_bounds__(256) void attn_kernel(const unsigned short* __restrict__ fbf,
                                                   const unsigned short* __restrict__ fbfT,
                                                   const float* __restrict__ feat,
                                                   const float* __restrict__ gamma_p,
                                                   float* __restrict__ out) {
  const int tid = threadIdx.x;
  const int lane = tid & 63;
  const int w = tid >> 6;
  const int b = blockIdx.x >> 6;
  const int i0 = (blockIdx.x & 63) << 6;

  const unsigned short* fb = fbf + b * (kC * kN);
  const unsigned short* fT = fbfT + b * (kN * kC);

  __shared__ unsigned short Qs[64 * 64];     // fbfT rows i0.., 8 chunks of 8 bf16, chunk^=(row&7)
  __shared__ unsigned short Ts[32 * 64];     // fbfT rows j0.., same swizzle
  __shared__ unsigned short Ns[64 * 32];     // fbf rows c, cols j0..+31, chunk(of 4)^=((c>>2)&3)
  __shared__ unsigned short Ps[4 * 16 * 40]; // per-wave P tile [16 i][32 j], stride 40
  __shared__ float l_all[64];
  __shared__ float epi[64 * 65];

  // stage Q
  {
    int r = tid >> 3, gc = tid & 7;
#pragma unroll
    for (int rep = 0; rep < 2; ++rep) {
      int row = r + rep * 32;
      uint4 v = *(const uint4*)(fT + (i0 + row) * 64 + gc * 8);
      *(uint4*)&Qs[row * 64 + ((gc ^ (row & 7)) * 8)] = v;
    }
  }
  // prefetch j-tile 0
  const int tr = tid >> 3, tgc = tid & 7;
  const int nc = tid >> 2, njc = tid & 3;
  uint4 tl = *(const uint4*)(fT + tr * 64 + tgc * 8);
  uint4 nl = *(const uint4*)(fb + nc * kN + njc * 8);

  const int lw = lane & 15, lg = lane >> 4;
  f32x4 oacc[4];
#pragma unroll
  for (int nt = 0; nt < 4; ++nt) oacc[nt] = (f32x4){0.f, 0.f, 0.f, 0.f};
  float lacc = 0.f;

  __syncthreads();
  short8 qf[2];
#pragma unroll
  for (int ch = 0; ch < 2; ++ch) {
    int row = w * 16 + lw;
    int gcq = lg + 4 * ch;
    qf[ch] = *(const short8*)&Qs[row * 64 + ((gcq ^ (row & 7)) * 8)];
  }

  for (int jt = 0; jt < 128; ++jt) {
    *(uint4*)&Ts[tr * 64 + ((tgc ^ (tr & 7)) * 8)] = tl;
    *(uint4*)&Ns[nc * 32 + ((njc ^ ((nc >> 2) & 3)) * 8)] = nl;
    __syncthreads();
    if (jt < 127) {
      int j0n = (jt + 1) << 5;
      tl = *(const uint4*)(fT + (j0n + tr) * 64 + tgc * 8);
      nl = *(const uint4*)(fb + nc * kN + j0n + njc * 8);
    }
    // S = f^T f tile, rows j (16x2), cols i (16)
    f32x4 s0 = {0.f, 0.f, 0.f, 0.f}, s1 = {0.f, 0.f, 0.f, 0.f};
    short8 a00 = *(const short8*)&Ts[lw * 64 + (((lg + 0) ^ (lw & 7)) * 8)];
    short8 a01 = *(const short8*)&Ts[lw * 64 + (((lg + 4) ^ (lw & 7)) * 8)];
    short8 a10 = *(const short8*)&Ts[(16 + lw) * 64 + (((lg + 0) ^ (lw & 7)) * 8)];
    short8 a11 = *(const short8*)&Ts[(16 + lw) * 64 + (((lg + 4) ^ (lw & 7)) * 8)];
    s0 = __builtin_amdgcn_mfma_f32_16x16x32_bf16(a00, qf[0], s0, 0, 0, 0);
    s0 = __builtin_amdgcn_mfma_f32_16x16x32_bf16(a01, qf[1], s0, 0, 0, 0);
    s1 = __builtin_amdgcn_mfma_f32_16x16x32_bf16(a10, qf[0], s1, 0, 0, 0);
    s1 = __builtin_amdgcn_mfma_f32_16x16x32_bf16(a11, qf[1], s1, 0, 0, 0);
    // p = exp(-E) (no row max needed: softmax shift-invariant; diag keeps rows sane)
    float p[8];
#pragma unroll
    for (int r = 0; r < 4; ++r) {
      p[r] = __expf(fminf(-s0[r], 80.f));
      p[4 + r] = __expf(fminf(-s1[r], 80.f));
    }
    float rsv = ((p[0] + p[1]) + (p[2] + p[3])) + ((p[4] + p[5]) + (p[6] + p[7]));
    rsv += __shfl_xor(rsv, 16);
    rsv += __shfl_xor(rsv, 32);
    lacc += rsv;  // running l for col i = lw (replicated over lane groups)
    // pack P -> per-wave LDS [i][j]
    unsigned short* pw = &Ps[w * 640 + lw * 40 + lg * 4];
    *(unsigned int*)(pw + 0) = pkbf(p[0], p[1]);
    *(unsigned int*)(pw + 2) = pkbf(p[2], p[3]);
    *(unsigned int*)(pw + 16) = pkbf(p[4], p[5]);
    *(unsigned int*)(pw + 18) = pkbf(p[6], p[7]);
    // PV: D = P * V^T, rows i, cols c
    short8 pf = *(const short8*)&Ps[w * 640 + lw * 40 + lg * 8];
#pragma unroll
    for (int nt = 0; nt < 4; ++nt) {
      int row = nt * 16 + lw;
      short8 vf = *(const short8*)&Ns[row * 32 + ((lg ^ ((row >> 2) & 3)) * 8)];
      oacc[nt] = __builtin_amdgcn_mfma_f32_16x16x32_bf16(pf, vf, oacc[nt], 0, 0, 0);
    }
    __syncthreads();
  }

  if (lane < 16) l_all[w * 16 + lane] = lacc;
  __syncthreads();
  const float g = gamma_p[0];
  float rl[4];
#pragma unroll
  for (int r = 0; r < 4; ++r) rl[r] = 1.f / l_all[w * 16 + lg * 4 + r];
#pragma unroll
  for (int nt = 0; nt < 4; ++nt)
#pragma unroll
    for (int r = 0; r < 4; ++r)
      epi[(nt * 16 + lw) * 65 + w * 16 + lg * 4 + r] = g * oacc[nt][r] * rl[r];
  __syncthreads();
  {
    const int c = tid >> 2, ib = (tid & 3) << 4;
    const float* fp = feat + ((b * kC + c) * kN) + i0 + ib;
    float* op = out + ((b * kC + c) * kN) + i0 + ib;
#pragma unroll
    for (int v = 0; v < 4; ++v) {
      float4 fv = *(const float4*)(fp + v * 4);
      float4 ov;
      ov.x = epi[c * 65 + ib + v * 4 + 0] + fv.x;
      ov.y = epi[c * 65 + ib + v * 4 + 1] + fv.y;
      ov.z = epi[c * 65 + ib + v * 4 + 2] + fv.z;
      ov.w = epi[c * 65 + ib + v * 4 + 3] + fv.w;
      *(float4*)(op + v * 4) = ov;
    }
  }
}

extern "C" void kernel_launch(void* const* d_in, const int* in_sizes, int n_in,
                              void* d_out, int out_size, void* d_ws, size_t ws_size,
                              hipStream_t stream) {
  (void)in_sizes; (void)n_in; (void)out_size; (void)ws_size;
  const float* x        = (const float*)d_in[0];
  const float* conv_w   = (const float*)d_in[1];
  const float* conv_b   = (const float*)d_in[2];
  const float* bn_scale = (const float*)d_in[3];
  const float* bn_bias  = (const float*)d_in[4];
  const float* prelu_a  = (const float*)d_in[5];
  const float* gamma    = (const float*)d_in[6];
  float* out = (float*)d_out;

  float* feat = (float*)d_ws;                              // 1M f32
  unsigned short* fbf = (unsigned short*)(feat + kB * kC * kN);   // 1M bf16
  unsigned short* fbfT = fbf + kB * kC * kN;               // 1M bf16
  float* AB = (float*)(fbfT + kB * kC * kN);               // 128 f32
  float* wt = AB + 256;                                    // 36864 f32

  float* y = out;  // conv scratch in d_out; overwritten by attn at the end

  transpose_w_kernel<<<144, 256, 0, stream>>>(conv_w, wt);
  conv_kernel<<<kB * kH, 256, 0, stream>>>(x, wt, conv_b, y);
  stats_kernel<<<kC, 256, 0, stream>>>(y, bn_scale, bn_bias, AB);
  pack_kernel<<<kB * (kN / 64), 256, 0, stream>>>(y, AB, prelu_a, feat, fbf, fbfT);
  attn_kernel<<<kB * (kN / 64), 256, 0, stream>>>(fbf, fbfT, feat, gamma, out);
}

// Round 3
// 175.227 us; speedup vs baseline: 3.1798x; 1.1331x over previous
//
#include <hip/hip_runtime.h>

constexpr int kB = 4, kC = 64, kH = 64, kW = 64, kN = kH * kW;
constexpr float kEps = 1e-5f;

typedef __attribute__((ext_vector_type(8))) short short8;
typedef __attribute__((ext_vector_type(4))) float f32x4;

__device__ inline unsigned pkbf(float a, float b) {
  unsigned ua = __float_as_uint(a), ub = __float_as_uint(b);
  ua += 0x7fff + ((ua >> 16) & 1);
  ub += 0x7fff + ((ub >> 16) & 1);
  return (ua >> 16) | (ub & 0xffff0000u);
}

// ---- w[oc][ic][kh][kw] fp32 -> wA bf16 [oc][(kh*3+kw)*64 + ic]
__global__ __launch_bounds__(256) void prep_w_kernel(const float* __restrict__ w,
                                                     unsigned short* __restrict__ wA) {
  int idx = blockIdx.x * 256 + threadIdx.x;
  if (idx < 64 * 576) {
    int oc = idx / 576, r = idx - oc * 576;
    int khw = r >> 6, ic = r & 63;
    float v = w[(oc * 64 + ic) * 9 + khw];
    unsigned u = __float_as_uint(v);
    u += 0x7fff + ((u >> 16) & 1);
    wA[idx] = (unsigned short)(u >> 16);
  }
}

// ---- conv 3x3 SAME + bias via bf16 MFMA implicit GEMM. block=(b,h), 4 waves.
// D[oc 16 per wave][w 64], K = 576 = (kh,kw,ic)
__global__ __launch_bounds__(256) void conv_kernel(const float* __restrict__ x,
                                                   const unsigned short* __restrict__ wA,
                                                   const float* __restrict__ bias,
                                                   float* __restrict__ y) {
  const int tid = threadIdx.x;
  const int lane = tid & 63;
  const int wv = tid >> 6;
  const int b = blockIdx.x >> 6;
  const int h = blockIdx.x & 63;
  const int lw = lane & 15, lg = lane >> 4;

  // [kh][wc 0..65][ic], ic-chunk(8) xor-swizzled by (wc&7); dword = ic pair
  __shared__ __align__(16) unsigned short xt[3 * 66 * 64];

  if (tid < 192) {  // zero pads wc=0,65
    int kh = tid >> 6, t2 = tid & 63;
    int wc = (t2 & 1) ? 65 : 0;
    int icp = t2 >> 1;
    *(unsigned*)&xt[(kh * 66 + wc) * 64 + (((icp >> 2) ^ (wc & 7)) * 8 + (icp & 3) * 2)] = 0u;
  }
#pragma unroll
  for (int rep = 0; rep < 6; ++rep) {  // 1536 (kh,icpair,w4) units
    int p = rep * 256 + tid;
    int kh = p >> 9;
    int q = p & 511;
    int icp = q >> 4;
    int w4 = (q & 15) << 2;
    int hh = h + kh - 1;
    float4 va = {0.f, 0.f, 0.f, 0.f}, vb = {0.f, 0.f, 0.f, 0.f};
    if (hh >= 0 && hh < 64) {
      va = *(const float4*)&x[((b * 64 + icp * 2) * 64 + hh) * 64 + w4];
      vb = *(const float4*)&x[((b * 64 + icp * 2 + 1) * 64 + hh) * 64 + w4];
    }
    float av[4] = {va.x, va.y, va.z, va.w};
    float bv4[4] = {vb.x, vb.y, vb.z, vb.w};
#pragma unroll
    for (int j = 0; j < 4; ++j) {
      int wc = 1 + w4 + j;
      *(unsigned*)&xt[(kh * 66 + wc) * 64 + (((icp >> 2) ^ (wc & 7)) * 8 + (icp & 3) * 2)] =
          pkbf(av[j], bv4[j]);
    }
  }
  __syncthreads();

  f32x4 acc[4];
#pragma unroll
  for (int nt = 0; nt < 4; ++nt) acc[nt] = (f32x4){0.f, 0.f, 0.f, 0.f};
  const int oc0 = wv * 16;
#pragma unroll
  for (int kc = 0; kc < 18; ++kc) {
    const int khw = kc >> 1;
    const int kh = khw / 3, kw = khw % 3;
    short8 af = *(const short8*)&wA[(oc0 + lw) * 576 + kc * 32 + lg * 8];
#pragma unroll
    for (int nt = 0; nt < 4; ++nt) {
      int wc = nt * 16 + lw + kw;
      short8 bf = *(const short8*)&xt[(kh * 66 + wc) * 64 + ((((kc & 1) * 4 + lg) ^ (wc & 7)) * 8)];
      acc[nt] = __builtin_amdgcn_mfma_f32_16x16x32_bf16(af, bf, acc[nt], 0, 0, 0);
    }
  }
  float bvv[4];
#pragma unroll
  for (int r = 0; r < 4; ++r) bvv[r] = bias[oc0 + lg * 4 + r];
#pragma unroll
  for (int nt = 0; nt < 4; ++nt)
#pragma unroll
    for (int r = 0; r < 4; ++r) {
      int oc = oc0 + lg * 4 + r;
      y[((b * 64 + oc) * 64 + h) * 64 + nt * 16 + lw] = acc[nt][r] + bvv[r];
    }
}

// ---- per-channel batch stats -> A[c], B[c]
__global__ __launch_bounds__(256) void stats_kernel(const float* __restrict__ y,
                                                    const float* __restrict__ scale,
                                                    const float* __restrict__ bias,
                                                    float* __restrict__ AB) {
  const int c = blockIdx.x;
  const int tid = threadIdx.x;
  float s = 0.f, s2 = 0.f;
  for (int b = 0; b < kB; ++b) {
    const float* p = y + (b * kC + c) * kN;
    for (int i = tid * 4; i < kN; i += 1024) {
      float4 v = *(const float4*)(p + i);
      s += v.x + v.y + v.z + v.w;
      s2 += v.x * v.x + v.y * v.y + v.z * v.z + v.w * v.w;
    }
  }
  __shared__ float rs[256], rq[256];
  rs[tid] = s;
  rq[tid] = s2;
  __syncthreads();
  for (int off = 128; off > 0; off >>= 1) {
    if (tid < off) { rs[tid] += rs[tid + off]; rq[tid] += rq[tid + off]; }
    __syncthreads();
  }
  if (tid == 0) {
    const float inv_n = 1.f / (float)(kB * kN);
    float mean = rs[0] * inv_n;
    float var = rq[0] * inv_n - mean * mean;
    float A = scale[c] * rsqrtf(var + kEps);
    AB[c] = A;
    AB[kC + c] = bias[c] - mean * A;
  }
}

// ---- BN + PReLU -> feat (f32 [c][n]), fbf (bf16 [c][n]), fbfT (bf16 [n][c])
__global__ __launch_bounds__(256) void pack_kernel(const float* __restrict__ y,
                                                   const float* __restrict__ AB,
                                                   const float* __restrict__ pa,
                                                   float* __restrict__ feat,
                                                   unsigned short* __restrict__ fbf,
                                                   unsigned short* __restrict__ fbfT) {
  __shared__ float ls[64 * 65];
  const int tid = threadIdx.x;
  const int b = blockIdx.x >> 6;
  const int n0 = (blockIdx.x & 63) << 6;
  {
    const int c = tid >> 2, nj = (tid & 3) << 4;
    const float A = AB[c], Bc = AB[kC + c], a = pa[0];
    const float* yp = y + ((b * kC + c) * kN) + n0 + nj;
    float f[16];
#pragma unroll
    for (int v = 0; v < 4; ++v) {
      float4 xv = *(const float4*)(yp + v * 4);
      float t;
      t = fmaf(A, xv.x, Bc); f[v * 4 + 0] = t >= 0.f ? t : a * t;
      t = fmaf(A, xv.y, Bc); f[v * 4 + 1] = t >= 0.f ? t : a * t;
      t = fmaf(A, xv.z, Bc); f[v * 4 + 2] = t >= 0.f ? t : a * t;
      t = fmaf(A, xv.w, Bc); f[v * 4 + 3] = t >= 0.f ? t : a * t;
    }
    float* fo = feat + ((b * kC + c) * kN) + n0 + nj;
#pragma unroll
    for (int v = 0; v < 4; ++v) {
      float4 fv = {f[v * 4 + 0], f[v * 4 + 1], f[v * 4 + 2], f[v * 4 + 3]};
      *(float4*)(fo + v * 4) = fv;
    }
    unsigned short* fbp = fbf + ((b * kC + c) * kN) + n0 + nj;
    uint4 p0 = {pkbf(f[0], f[1]), pkbf(f[2], f[3]), pkbf(f[4], f[5]), pkbf(f[6], f[7])};
    uint4 p1 = {pkbf(f[8], f[9]), pkbf(f[10], f[11]), pkbf(f[12], f[13]), pkbf(f[14], f[15])};
    *(uint4*)(fbp) = p0;
    *(uint4*)(fbp + 8) = p1;
#pragma unroll
    for (int v = 0; v < 16; ++v) ls[c * 65 + nj + v] = f[v];
  }
  __syncthreads();
  {
    const int n = tid >> 2, cc = (tid & 3) << 4;
    float g[16];
#pragma unroll
    for (int v = 0; v < 16; ++v) g[v] = ls[(cc + v) * 65 + n];
    unsigned short* ft = fbfT + b * (kN * kC) + (n0 + n) * 64 + cc;
    uint4 o0 = {pkbf(g[0], g[1]), pkbf(g[2], g[3]), pkbf(g[4], g[5]), pkbf(g[6], g[7])};
    uint4 o1 = {pkbf(g[8], g[9]), pkbf(g[10], g[11]), pkbf(g[12], g[13]), pkbf(g[14], g[15])};
    *(uint4*)(ft) = o0;
    *(uint4*)(ft + 8) = o1;
  }
}

// ---- MFMA flash attention with j-split partials. block=(b,it,s); 4 waves:
// wave = (ih,jh): 32i x 32j S tile, j-tile 64 per iter. Writes Op/lp partials.
__global__ __launch_bounds__(256, 4) void attn_kernel(const unsigned short* __restrict__ fbf,
                                                      const unsigned short* __restrict__ fbfT,
                                                      float* __restrict__ Op,
                                                      float* __restrict__ lp,
                                                      int log2split) {
  const int tid = threadIdx.x;
  const int lane = tid & 63;
  const int w = tid >> 6;
  const int ih = w >> 1, jh = w & 1;
  const int bx = blockIdx.x;
  const int s = bx & ((1 << log2split) - 1);
  const int it = (bx >> log2split) & 63;
  const int b = bx >> (log2split + 6);
  const int i0 = it << 6;
  const int nj = 64 >> log2split;  // 64-wide j-tiles per block
  const int jt0 = s * nj;
  const int lw = lane & 15, lg = lane >> 4;

  const unsigned short* fb = fbf + b * (kC * kN);
  const unsigned short* fT = fbfT + b * (kN * kC);

  __shared__ __align__(16) char smem[34816];
  unsigned short* Qs = (unsigned short*)smem;            // [64][64] sw by row&7
  unsigned short* Ts = (unsigned short*)(smem + 8192);   // [64][64] sw
  unsigned short* Ns = (unsigned short*)(smem + 16384);  // [64][64] sw
  unsigned short* Ps = (unsigned short*)(smem + 24576);  // 4 waves x [32][40]
  float* epi = (float*)smem;                             // [64][68] (aliases, post-loop)
  __shared__ float l_part[2][64];

  // stage Q
#pragma unroll
  for (int rep = 0; rep < 2; ++rep) {
    int idx = rep * 256 + tid;
    int row = idx >> 3, ch = idx & 7;
    uint4 v = *(const uint4*)&fT[(i0 + row) * 64 + ch * 8];
    *(uint4*)&Qs[row * 64 + ((ch ^ (row & 7)) * 8)] = v;
  }
  // prefetch first j-tile
  uint4 tl[2], nl[2];
  {
    int j0 = jt0 << 6;
#pragma unroll
    for (int rep = 0; rep < 2; ++rep) {
      int idx = rep * 256 + tid;
      int row = idx >> 3, ch = idx & 7;
      tl[rep] = *(const uint4*)&fT[(j0 + row) * 64 + ch * 8];
      nl[rep] = *(const uint4*)&fb[row * kN + j0 + ch * 8];
    }
  }
  __syncthreads();
  short8 qf[2][2];
#pragma unroll
  for (int ti = 0; ti < 2; ++ti)
#pragma unroll
    for (int kc = 0; kc < 2; ++kc) {
      int row = ih * 32 + ti * 16 + lw;
      qf[ti][kc] = *(const short8*)&Qs[row * 64 + (((kc * 4 + lg) ^ (row & 7)) * 8)];
    }

  f32x4 oacc[2][4];
#pragma unroll
  for (int ti = 0; ti < 2; ++ti)
#pragma unroll
    for (int ct = 0; ct < 4; ++ct) oacc[ti][ct] = (f32x4){0.f, 0.f, 0.f, 0.f};
  float lacc0 = 0.f, lacc1 = 0.f;

  for (int jt = jt0; jt < jt0 + nj; ++jt) {
#pragma unroll
    for (int rep = 0; rep < 2; ++rep) {
      int idx = rep * 256 + tid;
      int row = idx >> 3, ch = idx & 7;
      *(uint4*)&Ts[row * 64 + ((ch ^ (row & 7)) * 8)] = tl[rep];
      *(uint4*)&Ns[row * 64 + ((ch ^ (row & 7)) * 8)] = nl[rep];
    }
    __syncthreads();
    if (jt + 1 < jt0 + nj) {
      int j0n = (jt + 1) << 6;
#pragma unroll
      for (int rep = 0; rep < 2; ++rep) {
        int idx = rep * 256 + tid;
        int row = idx >> 3, ch = idx & 7;
        tl[rep] = *(const uint4*)&fT[(j0n + row) * 64 + ch * 8];
        nl[rep] = *(const uint4*)&fb[row * kN + j0n + ch * 8];
      }
    }
    // S tiles: D[row=j][col=i], A = Ts j-rows, B = qf
    short8 aT[2][2];
#pragma unroll
    for (int tj = 0; tj < 2; ++tj)
#pragma unroll
      for (int kc = 0; kc < 2; ++kc) {
        int row = jh * 32 + tj * 16 + lw;
        aT[tj][kc] = *(const short8*)&Ts[row * 64 + (((kc * 4 + lg) ^ (row & 7)) * 8)];
      }
    f32x4 sv[2][2];
#pragma unroll
    for (int ti = 0; ti < 2; ++ti)
#pragma unroll
      for (int tj = 0; tj < 2; ++tj) {
        f32x4 z = (f32x4){0.f, 0.f, 0.f, 0.f};
        z = __builtin_amdgcn_mfma_f32_16x16x32_bf16(aT[tj][0], qf[ti][0], z, 0, 0, 0);
        z = __builtin_amdgcn_mfma_f32_16x16x32_bf16(aT[tj][1], qf[ti][1], z, 0, 0, 0);
        sv[ti][tj] = z;
      }
    // exp(-E), l partial sums, P -> per-wave LDS [i][j]
    unsigned short* pw = Ps + w * 1280;
    float rs0 = 0.f, rs1 = 0.f;
#pragma unroll
    for (int ti = 0; ti < 2; ++ti)
#pragma unroll
      for (int tj = 0; tj < 2; ++tj) {
        float p0 = __expf(fminf(-sv[ti][tj][0], 80.f));
        float p1 = __expf(fminf(-sv[ti][tj][1], 80.f));
        float p2 = __expf(fminf(-sv[ti][tj][2], 80.f));
        float p3 = __expf(fminf(-sv[ti][tj][3], 80.f));
        if (ti == 0) rs0 += (p0 + p1) + (p2 + p3);
        else rs1 += (p0 + p1) + (p2 + p3);
        int base = (ti * 16 + lw) * 40 + tj * 16 + lg * 4;
        *(unsigned*)&pw[base] = pkbf(p0, p1);
        *(unsigned*)&pw[base + 2] = pkbf(p2, p3);
      }
    rs0 += __shfl_xor(rs0, 16);
    rs0 += __shfl_xor(rs0, 32);
    rs1 += __shfl_xor(rs1, 16);
    rs1 += __shfl_xor(rs1, 32);
    lacc0 += rs0;
    lacc1 += rs1;
    // PV: D[row=i][col=c], A = P [i][j], B = Ns c-rows (k = j)
    short8 pa[2];
#pragma unroll
    for (int ti = 0; ti < 2; ++ti)
      pa[ti] = *(const short8*)&pw[(ti * 16 + lw) * 40 + lg * 8];
#pragma unroll
    for (int ct = 0; ct < 4; ++ct) {
      int row = ct * 16 + lw;
      short8 vf = *(const short8*)&Ns[row * 64 + (((jh * 4 + lg) ^ (row & 7)) * 8)];
#pragma unroll
      for (int ti = 0; ti < 2; ++ti)
        oacc[ti][ct] = __builtin_amdgcn_mfma_f32_16x16x32_bf16(pa[ti], vf, oacc[ti][ct], 0, 0, 0);
    }
    __syncthreads();
  }

  if (lane < 16) {
    l_part[jh][ih * 32 + lane] = lacc0;
    l_part[jh][ih * 32 + 16 + lane] = lacc1;
  }
  __syncthreads();  // loop LDS dead; epi aliases Qs/Ts
  if (jh == 0) {
#pragma unroll
    for (int ti = 0; ti < 2; ++ti)
#pragma unroll
      for (int ct = 0; ct < 4; ++ct)
#pragma unroll
        for (int r = 0; r < 4; ++r)
          epi[(ct * 16 + lw) * 68 + ih * 32 + ti * 16 + lg * 4 + r] = oacc[ti][ct][r];
  }
  __syncthreads();
  if (jh == 1) {
#pragma unroll
    for (int ti = 0; ti < 2; ++ti)
#pragma unroll
      for (int ct = 0; ct < 4; ++ct)
#pragma unroll
        for (int r = 0; r < 4; ++r)
          epi[(ct * 16 + lw) * 68 + ih * 32 + ti * 16 + lg * 4 + r] += oacc[ti][ct][r];
  }
  __syncthreads();
  if (tid < 64) lp[bx * 64 + tid] = l_part[0][tid] + l_part[1][tid];
#pragma unroll
  for (int rep = 0; rep < 4; ++rep) {
    int flat4 = rep * 256 + tid;
    int c = flat4 >> 4, i4 = (flat4 & 15) << 2;
    float4 v = *(const float4*)&epi[c * 68 + i4];
    *(float4*)&Op[(size_t)bx * 4096 + c * 64 + i4] = v;
  }
}

// ---- merge j-split partials: out = gamma * (sum Op)/ (sum lp) + feat
__global__ __launch_bounds__(256) void combine_kernel(const float* __restrict__ Op,
                                                      const float* __restrict__ lp,
                                                      const float* __restrict__ feat,
                                                      const float* __restrict__ gamma_p,
                                                      float* __restrict__ out, int split) {
  const int tid = threadIdx.x;
  const int bx = blockIdx.x;  // b*64 + it
  const int b = bx >> 6, it = bx & 63;
  __shared__ float linv[64];
  if (tid < 64) {
    float s = 0.f;
    for (int k = 0; k < split; ++k) s += lp[(bx * split + k) * 64 + tid];
    linv[tid] = 1.f / s;
  }
  __syncthreads();
  const float g = gamma_p[0];
#pragma unroll
  for (int rep = 0; rep < 4; ++rep) {
    int flat4 = rep * 256 + tid;
    int c = flat4 >> 4, i4 = (flat4 & 15) << 2;
    float4 acc = {0.f, 0.f, 0.f, 0.f};
    for (int k = 0; k < split; ++k) {
      float4 v = *(const float4*)&Op[((size_t)bx * split + k) * 4096 + c * 64 + i4];
      acc.x += v.x; acc.y += v.y; acc.z += v.z; acc.w += v.w;
    }
    float4 fv = *(const float4*)&feat[(b * 64 + c) * 4096 + it * 64 + i4];
    float4 ov;
    ov.x = g * acc.x * linv[i4 + 0] + fv.x;
    ov.y = g * acc.y * linv[i4 + 1] + fv.y;
    ov.z = g * acc.z * linv[i4 + 2] + fv.z;
    ov.w = g * acc.w * linv[i4 + 3] + fv.w;
    *(float4*)&out[(b * 64 + c) * 4096 + it * 64 + i4] = ov;
  }
}

extern "C" void kernel_launch(void* const* d_in, const int* in_sizes, int n_in,
                              void* d_out, int out_size, void* d_ws, size_t ws_size,
                              hipStream_t stream) {
  (void)in_sizes; (void)n_in; (void)out_size;
  const float* x        = (const float*)d_in[0];
  const float* conv_w   = (const float*)d_in[1];
  const float* conv_b   = (const float*)d_in[2];
  const float* bn_scale = (const float*)d_in[3];
  const float* bn_bias  = (const float*)d_in[4];
  const float* prelu_a  = (const float*)d_in[5];
  const float* gamma    = (const float*)d_in[6];
  float* out = (float*)d_out;

  float* feat = (float*)d_ws;                                   // 1M f32
  unsigned short* fbf  = (unsigned short*)(feat + kB * kC * kN);  // 1M bf16
  unsigned short* fbfT = fbf + kB * kC * kN;                    // 1M bf16
  float* AB = (float*)(fbfT + kB * kC * kN);                    // 256 f32
  unsigned short* wAp = (unsigned short*)(AB + 256);            // 36864 bf16
  float* Op = (float*)(wAp + 36864);                            // split*256*4096 f32
  // ws budget: pick split=4 if it fits, else split=1
  int log2split = 2;
  size_t need = (size_t)8463360 + (size_t)4 * (4194304 + 65536);
  if (ws_size < need) log2split = 0;
  int split = 1 << log2split;
  float* lp = Op + (size_t)split * 256 * 4096;

  float* y = out;  // conv scratch in d_out; overwritten by combine at the end

  prep_w_kernel<<<144, 256, 0, stream>>>(conv_w, wAp);
  conv_kernel<<<kB * kH, 256, 0, stream>>>(x, wAp, conv_b, y);
  stats_kernel<<<kC, 256, 0, stream>>>(y, bn_scale, bn_bias, AB);
  pack_kernel<<<kB * (kN / 64), 256, 0, stream>>>(y, AB, prelu_a, feat, fbf, fbfT);
  attn_kernel<<<kB * 64 * split, 256, 0, stream>>>(fbf, fbfT, Op, lp, log2split);
  combine_kernel<<<kB * 64, 256, 0, stream>>>(Op, lp, feat, gamma, out, split);
}

// Round 4
// 124.084 us; speedup vs baseline: 4.4904x; 1.4122x over previous
//
#include <hip/hip_runtime.h>

constexpr int kB = 4, kC = 64, kH = 64, kW = 64, kN = kH * kW;
constexpr float kEps = 1e-5f;
constexpr int SPLIT = 4;

typedef __attribute__((ext_vector_type(8))) short short8;
typedef __attribute__((ext_vector_type(4))) float f32x4;
typedef unsigned short u16;

__device__ inline unsigned pkbf(float a, float b) {  // RNE pack (pack path only)
  unsigned ua = __float_as_uint(a), ub = __float_as_uint(b);
  ua += 0x7fff + ((ua >> 16) & 1);
  ub += 0x7fff + ((ub >> 16) & 1);
  return (ua >> 16) | (ub & 0xffff0000u);
}

// ---- w[oc][ic][3][3] fp32 -> wA bf16 [oc][khw*64 + ic]
__global__ __launch_bounds__(256) void prep_w_kernel(const float* __restrict__ w,
                                                     u16* __restrict__ wA) {
  int idx = blockIdx.x * 256 + threadIdx.x;
  if (idx < 64 * 576) {
    int oc = idx / 576, r = idx - oc * 576;
    int khw = r >> 6, ic = r & 63;
    float v = w[(oc * 64 + ic) * 9 + khw];
    unsigned u = __float_as_uint(v);
    u += 0x7fff + ((u >> 16) & 1);
    wA[idx] = (u16)(u >> 16);
  }
}

// ---- conv 3x3 SAME + bias, bf16 MFMA implicit GEMM. block=(b,h,whalf), 4 waves.
__global__ __launch_bounds__(256) void conv_kernel(const float* __restrict__ x,
                                                   const u16* __restrict__ wA,
                                                   const float* __restrict__ bias,
                                                   float* __restrict__ y) {
  const int tid = threadIdx.x;
  const int lane = tid & 63;
  const int wv = tid >> 6;
  const int bx = blockIdx.x;
  const int b = bx >> 7;
  const int h = (bx & 127) >> 1;
  const int w0 = (bx & 1) * 32;
  const int lw = lane & 15, lg = lane >> 4;

  // xt[kh][wc 0..39][ic], wc <-> w = w0-4+wc ; ic-chunk8 swizzled by wc&7
  __shared__ __align__(16) u16 xt[3 * 40 * 64];

#pragma unroll
  for (int rep = 0; rep < 4; ++rep) {
    int idx = rep * 256 + tid;
    if (idx < 960) {
      int kh = idx / 320;
      int t = idx - kh * 320;
      int gw = t >> 5, icp = t & 31;
      int wb = w0 - 4 + gw * 4;
      int hh = h + kh - 1;
      float4 va = {0.f, 0.f, 0.f, 0.f}, vb = {0.f, 0.f, 0.f, 0.f};
      if (hh >= 0 && hh < 64 && wb >= 0 && wb < 64) {
        va = *(const float4*)&x[((b * 64 + icp * 2) * 64 + hh) * 64 + wb];
        vb = *(const float4*)&x[((b * 64 + icp * 2 + 1) * 64 + hh) * 64 + wb];
      }
      float av[4] = {va.x, va.y, va.z, va.w};
      float bv[4] = {vb.x, vb.y, vb.z, vb.w};
#pragma unroll
      for (int j = 0; j < 4; ++j) {
        int wc = gw * 4 + j;
        *(unsigned*)&xt[(kh * 40 + wc) * 64 + (((icp >> 2) ^ (wc & 7)) * 8 + (icp & 3) * 2)] =
            pkbf(av[j], bv[j]);
      }
    }
  }
  __syncthreads();

  const int oc0 = wv * 16;
  short8 af[18];
#pragma unroll
  for (int kc = 0; kc < 18; ++kc)
    af[kc] = *(const short8*)&wA[(oc0 + lw) * 576 + kc * 32 + lg * 8];

  f32x4 acc[2];
  acc[0] = (f32x4){0.f, 0.f, 0.f, 0.f};
  acc[1] = (f32x4){0.f, 0.f, 0.f, 0.f};
#pragma unroll
  for (int kc = 0; kc < 18; ++kc) {
    const int khw = kc >> 1;
    const int kh = khw / 3, kwv = khw % 3;
#pragma unroll
    for (int nt = 0; nt < 2; ++nt) {
      int wc = nt * 16 + lw + kwv + 3;
      short8 bf = *(const short8*)&xt[(kh * 40 + wc) * 64 + ((((kc & 1) * 4 + lg) ^ (wc & 7)) * 8)];
      acc[nt] = __builtin_amdgcn_mfma_f32_16x16x32_bf16(af[kc], bf, acc[nt], 0, 0, 0);
    }
  }
#pragma unroll
  for (int nt = 0; nt < 2; ++nt)
#pragma unroll
    for (int r = 0; r < 4; ++r) {
      int oc = oc0 + lg * 4 + r;
      y[((b * 64 + oc) * 64 + h) * 64 + w0 + nt * 16 + lw] = acc[nt][r] + bias[oc];
    }
}

// ---- per-channel batch stats -> A[c], B[c]
__global__ __launch_bounds__(256) void stats_kernel(const float* __restrict__ y,
                                                    const float* __restrict__ scale,
                                                    const float* __restrict__ bias,
                                                    float* __restrict__ AB) {
  const int c = blockIdx.x;
  const int tid = threadIdx.x;
  float s = 0.f, s2 = 0.f;
  for (int b = 0; b < kB; ++b) {
    const float* p = y + (b * kC + c) * kN;
    for (int i = tid * 4; i < kN; i += 1024) {
      float4 v = *(const float4*)(p + i);
      s += v.x + v.y + v.z + v.w;
      s2 += v.x * v.x + v.y * v.y + v.z * v.z + v.w * v.w;
    }
  }
  __shared__ float rs[256], rq[256];
  rs[tid] = s;
  rq[tid] = s2;
  __syncthreads();
  for (int off = 128; off > 0; off >>= 1) {
    if (tid < off) { rs[tid] += rs[tid + off]; rq[tid] += rq[tid + off]; }
    __syncthreads();
  }
  if (tid == 0) {
    const float inv_n = 1.f / (float)(kB * kN);
    float mean = rs[0] * inv_n;
    float var = rq[0] * inv_n - mean * mean;
    float A = scale[c] * rsqrtf(var + kEps);
    AB[c] = A;
    AB[kC + c] = bias[c] - mean * A;
  }
}

// ---- BN + PReLU -> feat f32 [c][n]; fbfA (frag layout: pos=lane&15, ch=k);
//      fbfB (frag layout: ch=lane&15, pos=k)
__global__ __launch_bounds__(256) void pack_kernel(const float* __restrict__ y,
                                                   const float* __restrict__ AB,
                                                   const float* __restrict__ pa,
                                                   float* __restrict__ feat,
                                                   u16* __restrict__ fbfA,
                                                   u16* __restrict__ fbfB) {
  __shared__ float ls[64 * 65];
  const int tid = threadIdx.x;
  const int b = blockIdx.x >> 6;
  const int n0 = (blockIdx.x & 63) << 6;
  {
    const int c = tid >> 2, nj = (tid & 3) << 4;
    const float A = AB[c], Bc = AB[kC + c], a = pa[0];
    const float* yp = y + ((b * kC + c) * kN) + n0 + nj;
    float f[16];
#pragma unroll
    for (int v = 0; v < 4; ++v) {
      float4 xv = *(const float4*)(yp + v * 4);
      float t;
      t = fmaf(A, xv.x, Bc); f[v * 4 + 0] = t >= 0.f ? t : a * t;
      t = fmaf(A, xv.y, Bc); f[v * 4 + 1] = t >= 0.f ? t : a * t;
      t = fmaf(A, xv.z, Bc); f[v * 4 + 2] = t >= 0.f ? t : a * t;
      t = fmaf(A, xv.w, Bc); f[v * 4 + 3] = t >= 0.f ? t : a * t;
    }
    float* fo = feat + ((b * kC + c) * kN) + n0 + nj;
#pragma unroll
    for (int v = 0; v < 4; ++v) {
      float4 fv = {f[v * 4 + 0], f[v * 4 + 1], f[v * 4 + 2], f[v * 4 + 3]};
      *(float4*)(fo + v * 4) = fv;
    }
#pragma unroll
    for (int v = 0; v < 16; ++v) ls[c * 65 + nj + v] = f[v];
  }
  __syncthreads();
  {  // fbfA: chunk = (pt within block 0..3, kc 0..1); 64 lanes x 16B per chunk
    int chunk = tid >> 5, pt = chunk >> 1, kc = chunk & 1;
    int lp2 = (tid & 31) * 2;
    u16* dst = fbfA + ((size_t)((b * 256 + (n0 >> 4) + pt) * 2 + kc)) * 512;
#pragma unroll
    for (int e = 0; e < 2; ++e) {
      int L = lp2 + e;
      int n = pt * 16 + (L & 15);
      int cb = kc * 32 + (L >> 4) * 8;
      float v[8];
#pragma unroll
      for (int r = 0; r < 8; ++r) v[r] = ls[(cb + r) * 65 + n];
      uint4 o = {pkbf(v[0], v[1]), pkbf(v[2], v[3]), pkbf(v[4], v[5]), pkbf(v[6], v[7])};
      *(uint4*)&dst[L * 8] = o;
    }
  }
  {  // fbfB: chunk = (jt 0..1, ct 0..3)
    int chunk = tid >> 5, jt = chunk >> 2, ct = chunk & 3;
    int lp2 = (tid & 31) * 2;
    u16* dst = fbfB + ((size_t)((b * 128 + (n0 >> 5) + jt) * 4 + ct)) * 512;
#pragma unroll
    for (int e = 0; e < 2; ++e) {
      int L = lp2 + e;
      int c = ct * 16 + (L & 15);
      int nb = jt * 32 + (L >> 4) * 8;
      float v[8];
#pragma unroll
      for (int r = 0; r < 8; ++r) v[r] = ls[c * 65 + nb + r];
      uint4 o = {pkbf(v[0], v[1]), pkbf(v[2], v[3]), pkbf(v[4], v[5]), pkbf(v[6], v[7])};
      *(uint4*)&dst[L * 8] = o;
    }
  }
}

// ---- barrier-free MFMA flash attention. block=(b,itb,s); wave w owns i-64.
// All frags loaded straight from global (pre-permuted); only P round-trips LDS.
__global__ __launch_bounds__(256, 2) void attn_kernel(const u16* __restrict__ fbfA,
                                                      const u16* __restrict__ fbfB,
                                                      float* __restrict__ Op,
                                                      float* __restrict__ lp) {
  const int tid = threadIdx.x;
  const int lane = tid & 63;
  const int w = tid >> 6;
  const int bx = blockIdx.x;
  const int s = bx & 3, itb = (bx >> 2) & 15, b = bx >> 6;
  const int c15 = lane & 15, g = lane >> 4;

  __shared__ __align__(16) u16 Ps[4][64 * 40];
  u16* ps = &Ps[w][0];
  const int pw_off = c15 * 40 + g * 4;   // write base (elements)
  const int pr_off = c15 * 40 + g * 8;   // b128 read base

  const uint4* fA = (const uint4*)fbfA;
  const uint4* fB = (const uint4*)fbfB;

  // Q frags (negated so S = -E)
  uint4 qf[4][2];
  const int ptq = itb * 16 + w * 4;
#pragma unroll
  for (int it = 0; it < 4; ++it)
#pragma unroll
    for (int kc = 0; kc < 2; ++kc) {
      uint4 q = fA[(size_t)((b * 256 + ptq + it) * 2 + kc) * 64 + lane];
      q.x ^= 0x80008000u; q.y ^= 0x80008000u; q.z ^= 0x80008000u; q.w ^= 0x80008000u;
      qf[it][kc] = q;
    }

  const short8 ones = {0x3F80, 0x3F80, 0x3F80, 0x3F80, 0x3F80, 0x3F80, 0x3F80, 0x3F80};

  f32x4 oacc[4][4];
  f32x4 lacc[4];
#pragma unroll
  for (int it = 0; it < 4; ++it) {
    lacc[it] = (f32x4){0.f, 0.f, 0.f, 0.f};
#pragma unroll
    for (int ct = 0; ct < 4; ++ct) oacc[it][ct] = (f32x4){0.f, 0.f, 0.f, 0.f};
  }

#pragma unroll 2
  for (int jj = 0; jj < 32; ++jj) {
    const int j0 = (s * 32 + jj) * 32;
    // fragment loads (coalesced 1KB each, L1/L2-resident)
    const int ca = (b * 256 + (j0 >> 4)) * 2;
    uint4 a00 = fA[(size_t)(ca + 0) * 64 + lane];
    uint4 a01 = fA[(size_t)(ca + 1) * 64 + lane];
    uint4 a10 = fA[(size_t)(ca + 2) * 64 + lane];
    uint4 a11 = fA[(size_t)(ca + 3) * 64 + lane];
    const int cb = (b * 128 + (j0 >> 5)) * 4;
    uint4 v0 = fB[(size_t)(cb + 0) * 64 + lane];
    uint4 v1 = fB[(size_t)(cb + 1) * 64 + lane];
    uint4 v2 = fB[(size_t)(cb + 2) * 64 + lane];
    uint4 v3 = fB[(size_t)(cb + 3) * 64 + lane];

    // S^T tiles: D[m=j][n=i] = -E
    f32x4 sv[2][4];
#pragma unroll
    for (int it = 0; it < 4; ++it) {
      f32x4 z0 = (f32x4){0.f, 0.f, 0.f, 0.f};
      z0 = __builtin_amdgcn_mfma_f32_16x16x32_bf16(*(short8*)&a00, *(short8*)&qf[it][0], z0, 0, 0, 0);
      z0 = __builtin_amdgcn_mfma_f32_16x16x32_bf16(*(short8*)&a01, *(short8*)&qf[it][1], z0, 0, 0, 0);
      sv[0][it] = z0;
      f32x4 z1 = (f32x4){0.f, 0.f, 0.f, 0.f};
      z1 = __builtin_amdgcn_mfma_f32_16x16x32_bf16(*(short8*)&a10, *(short8*)&qf[it][0], z1, 0, 0, 0);
      z1 = __builtin_amdgcn_mfma_f32_16x16x32_bf16(*(short8*)&a11, *(short8*)&qf[it][1], z1, 0, 0, 0);
      sv[1][it] = z1;
    }
    // P = exp(S) packed to per-wave LDS [i][j] (v_perm RTZ bf16 pack)
#pragma unroll
    for (int it = 0; it < 4; ++it)
#pragma unroll
      for (int jt = 0; jt < 2; ++jt) {
        float p0 = __expf(sv[jt][it][0]);
        float p1 = __expf(sv[jt][it][1]);
        float p2 = __expf(sv[jt][it][2]);
        float p3 = __expf(sv[jt][it][3]);
        uint2 d;
        d.x = __builtin_amdgcn_perm(__float_as_uint(p1), __float_as_uint(p0), 0x07060302u);
        d.y = __builtin_amdgcn_perm(__float_as_uint(p3), __float_as_uint(p2), 0x07060302u);
        *(uint2*)&ps[pw_off + it * 640 + jt * 16] = d;
      }
    // PV + l (ones-frag row sums)
#pragma unroll
    for (int it = 0; it < 4; ++it) {
      short8 pf = *(const short8*)&ps[pr_off + it * 640];
      lacc[it] = __builtin_amdgcn_mfma_f32_16x16x32_bf16(pf, ones, lacc[it], 0, 0, 0);
      oacc[it][0] = __builtin_amdgcn_mfma_f32_16x16x32_bf16(pf, *(short8*)&v0, oacc[it][0], 0, 0, 0);
      oacc[it][1] = __builtin_amdgcn_mfma_f32_16x16x32_bf16(pf, *(short8*)&v1, oacc[it][1], 0, 0, 0);
      oacc[it][2] = __builtin_amdgcn_mfma_f32_16x16x32_bf16(pf, *(short8*)&v2, oacc[it][2], 0, 0, 0);
      oacc[it][3] = __builtin_amdgcn_mfma_f32_16x16x32_bf16(pf, *(short8*)&v3, oacc[it][3], 0, 0, 0);
    }
  }

  // write O partial [i][c] and l partial
  float* Ow = Op + (size_t)(bx * 4 + w) * 4096;
#pragma unroll
  for (int it = 0; it < 4; ++it)
#pragma unroll
    for (int ct = 0; ct < 4; ++ct)
#pragma unroll
      for (int r = 0; r < 4; ++r)
        Ow[(it * 16 + g * 4 + r) * 64 + ct * 16 + c15] = oacc[it][ct][r];
  if (c15 == 0) {
    float* lw_ = lp + (size_t)(bx * 4 + w) * 64;
#pragma unroll
    for (int it = 0; it < 4; ++it)
#pragma unroll
      for (int r = 0; r < 4; ++r) lw_[it * 16 + g * 4 + r] = lacc[it][r];
  }
}

// ---- combine: out[c][n] = gamma * (sum_s Op)/ (sum_s lp) + feat
__global__ __launch_bounds__(256) void combine_kernel(const float* __restrict__ Op,
                                                      const float* __restrict__ lp,
                                                      const float* __restrict__ feat,
                                                      const float* __restrict__ gamma_p,
                                                      float* __restrict__ out) {
  const int tid = threadIdx.x;
  const int bx = blockIdx.x;  // b*64 + it64
  const int b = bx >> 6, it64 = bx & 63;
  const int itb = it64 >> 2, w = it64 & 3;
  const int gbase = (b * 16 + itb) * 16 + w;  // + s*4
  __shared__ float tr[64 * 65];
  __shared__ float linv[64];
  if (tid < 64) {
    float sum = 0.f;
    for (int s = 0; s < SPLIT; ++s) sum += lp[(size_t)(gbase + s * 4) * 64 + tid];
    linv[tid] = 1.f / sum;
  }
  __syncthreads();
  const float gm = gamma_p[0];
#pragma unroll
  for (int rr = 0; rr < 4; ++rr) {
    int flat4 = rr * 256 + tid;
    int i = flat4 >> 4, c4 = (flat4 & 15) * 4;
    float4 acc = {0.f, 0.f, 0.f, 0.f};
    for (int s = 0; s < SPLIT; ++s) {
      float4 v = *(const float4*)&Op[(size_t)(gbase + s * 4) * 4096 + i * 64 + c4];
      acc.x += v.x; acc.y += v.y; acc.z += v.z; acc.w += v.w;
    }
    float sc = gm * linv[i];
    tr[(c4 + 0) * 65 + i] = acc.x * sc;
    tr[(c4 + 1) * 65 + i] = acc.y * sc;
    tr[(c4 + 2) * 65 + i] = acc.z * sc;
    tr[(c4 + 3) * 65 + i] = acc.w * sc;
  }
  __syncthreads();
#pragma unroll
  for (int rr = 0; rr < 4; ++rr) {
    int flat4 = rr * 256 + tid;
    int c = flat4 >> 4, i4 = (flat4 & 15) * 4;
    float4 fv = *(const float4*)&feat[(size_t)(b * 64 + c) * 4096 + it64 * 64 + i4];
    float4 ov;
    ov.x = tr[c * 65 + i4 + 0] + fv.x;
    ov.y = tr[c * 65 + i4 + 1] + fv.y;
    ov.z = tr[c * 65 + i4 + 2] + fv.z;
    ov.w = tr[c * 65 + i4 + 3] + fv.w;
    *(float4*)&out[(size_t)(b * 64 + c) * 4096 + it64 * 64 + i4] = ov;
  }
}

extern "C" void kernel_launch(void* const* d_in, const int* in_sizes, int n_in,
                              void* d_out, int out_size, void* d_ws, size_t ws_size,
                              hipStream_t stream) {
  (void)in_sizes; (void)n_in; (void)out_size; (void)ws_size;
  const float* x        = (const float*)d_in[0];
  const float* conv_w   = (const float*)d_in[1];
  const float* conv_b   = (const float*)d_in[2];
  const float* bn_scale = (const float*)d_in[3];
  const float* bn_bias  = (const float*)d_in[4];
  const float* prelu_a  = (const float*)d_in[5];
  const float* gamma    = (const float*)d_in[6];
  float* out = (float*)d_out;

  float* feat = (float*)d_ws;                          // 1,048,576 f32
  u16* fbfA = (u16*)(feat + kB * kC * kN);             // 1,048,576 u16
  u16* fbfB = fbfA + kB * kC * kN;                     // 1,048,576 u16
  float* AB = (float*)(fbfB + kB * kC * kN);           // 256 f32
  u16* wA = (u16*)(AB + 256);                          // 36,864 u16
  float* Op = (float*)(wA + 36864);                    // 256*4*4096 f32 (16 MB)
  float* lp = Op + (size_t)256 * 4 * 4096;             // 65,536 f32

  float* y = out;  // conv scratch in d_out; overwritten by combine at the end

  prep_w_kernel<<<144, 256, 0, stream>>>(conv_w, wA);
  conv_kernel<<<kB * kH * 2, 256, 0, stream>>>(x, wA, conv_b, y);
  stats_kernel<<<kC, 256, 0, stream>>>(y, bn_scale, bn_bias, AB);
  pack_kernel<<<kB * (kN / 64), 256, 0, stream>>>(y, AB, prelu_a, feat, fbfA, fbfB);
  attn_kernel<<<kB * 16 * SPLIT, 256, 0, stream>>>(fbfA, fbfB, Op, lp);
  combine_kernel<<<kB * 64, 256, 0, stream>>>(Op, lp, feat, gamma, out);
}